// Round 13
// baseline (98.522 us; speedup 1.0000x reference)
//
#include <hip/hip_runtime.h>

#define B 8
#define N 2048
#define KF 256
#define DF 64
#define LOG2E 1.44269504088896340736f
#define IC 8
#define ICH (N / IC)   // 256

typedef __attribute__((ext_vector_type(8))) short short8;   // 8 bf16 (4 VGPRs)
typedef __attribute__((ext_vector_type(4))) float float4v;  // MFMA C/D frag

__device__ __forceinline__ float fexp2(float x) {
#if __has_builtin(__builtin_amdgcn_exp2f)
    return __builtin_amdgcn_exp2f(x);
#else
    return exp2f(x);
#endif
}
__device__ __forceinline__ float eluf(float x) {
    return x > 0.f ? x : fexp2(x * LOG2E) - 1.0f;
}
// float -> bf16 bits, round-half-up
__device__ __forceinline__ short bf16r(float x) {
    unsigned u = __float_as_uint(x);
    return (short)((u + 0x8000u) >> 16);
}
#define DOT4(c, u, p) \
    p = fmaf(c.x, u.x, fmaf(c.y, u.y, fmaf(c.z, u.z, fmaf(c.w, u.w, p))));

// ---- A: Wh = h@W via MFMA + fused f1/f2 + fused W-prep (R11 structure).
// 512 blocks x 32 rows, K-split 4 across waves. Emits flat WhT[b][d][j]. ----
__global__ __launch_bounds__(256) void k_wh(const float* __restrict__ h,
                                            const float* __restrict__ W,
                                            const float* __restrict__ a,
                                            short* __restrict__ WhT,
                                            float* __restrict__ f1,
                                            float* __restrict__ f2) {
    __shared__ __align__(16) unsigned char smem[34816];  // phase union
    short* lwt  = (short*)smem;               // A: [64 n][256 k] bf16 W^T (32 KB)
    float* lv   = (float*)(smem + 32768);     // A: [2][256] v1,v2 (2 KB)
    float* lred = (float*)smem;               // B: [4 wv][16*66] (16.9 KB)
    float* lp   = (float*)(smem + 16896);     // B: [2][4][16]

    int t = threadIdx.x;
    int wv = t >> 6, lane = t & 63;
    int n15 = lane & 15, q = lane >> 4;
    int bx = blockIdx.x;

    // issue tile-0 h loads early (independent of W staging)
    const float* hr = h + ((long)bx * 32 + n15) * KF + wv * 64 + q * 8;
    float4 c0 = *(const float4*)(hr);
    float4 c1 = *(const float4*)(hr + 4);
    float4 c2 = *(const float4*)(hr + 32);
    float4 c3 = *(const float4*)(hr + 36);

    // ---- in-block W prep: thread t owns W row k=t ----
    {
        const float4* wr4 = (const float4*)(W + t * DF);
        float s1 = 0.f, s2 = 0.f;
        #pragma unroll
        for (int c = 0; c < 16; c++) {
            float4 w4 = wr4[c];
            float4 a1v = *(const float4*)(a + 4 * c);        // uniform -> s_load
            float4 a2v = *(const float4*)(a + DF + 4 * c);
            lwt[(4 * c + 0) * 256 + t] = bf16r(w4.x);        // 2-way write: free
            lwt[(4 * c + 1) * 256 + t] = bf16r(w4.y);
            lwt[(4 * c + 2) * 256 + t] = bf16r(w4.z);
            lwt[(4 * c + 3) * 256 + t] = bf16r(w4.w);
            s1 = fmaf(w4.x, a1v.x, fmaf(w4.y, a1v.y, fmaf(w4.z, a1v.z, fmaf(w4.w, a1v.w, s1))));
            s2 = fmaf(w4.x, a2v.x, fmaf(w4.y, a2v.y, fmaf(w4.z, a2v.z, fmaf(w4.w, a2v.w, s2))));
        }
        lv[t] = s1;
        lv[256 + t] = s2;
    }
    __syncthreads();

    // hoist loop-invariant B-frags + v12 (one-time LDS reads)
    const short* bq = lwt + n15 * 256 + wv * 64 + q * 8;
    short8 s0b0 = *(const short8*)(bq);
    short8 s0b1 = *(const short8*)(bq + 16 * 256);
    short8 s0b2 = *(const short8*)(bq + 32 * 256);
    short8 s0b3 = *(const short8*)(bq + 48 * 256);
    short8 s1b0 = *(const short8*)(bq + 32);
    short8 s1b1 = *(const short8*)(bq + 16 * 256 + 32);
    short8 s1b2 = *(const short8*)(bq + 32 * 256 + 32);
    short8 s1b3 = *(const short8*)(bq + 48 * 256 + 32);
    const float* vv = lv + wv * 64 + q * 8;
    float4 u00 = *(const float4*)(vv);
    float4 u01 = *(const float4*)(vv + 4);
    float4 u10 = *(const float4*)(vv + 32);
    float4 u11 = *(const float4*)(vv + 36);
    float4 x00 = *(const float4*)(vv + 256);
    float4 x01 = *(const float4*)(vv + 256 + 4);
    float4 x10 = *(const float4*)(vv + 256 + 32);
    float4 x11 = *(const float4*)(vv + 256 + 36);
    __syncthreads();   // lwt/lv dead; lred region reusable

    #pragma unroll
    for (int rt = 0; rt < 2; rt++) {
        float4 m0, m1, m2, m3;
        if (rt < 1) {                         // prefetch next 16-row tile
            const float* hn = hr + 16 * KF;
            m0 = *(const float4*)(hn);
            m1 = *(const float4*)(hn + 4);
            m2 = *(const float4*)(hn + 32);
            m3 = *(const float4*)(hn + 36);
        }
        float p1 = 0.f, p2 = 0.f;
        DOT4(c0, u00, p1) DOT4(c1, u01, p1) DOT4(c2, u10, p1) DOT4(c3, u11, p1)
        DOT4(c0, x00, p2) DOT4(c1, x01, p2) DOT4(c2, x10, p2) DOT4(c3, x11, p2)

        short8 af0 = { bf16r(c0.x), bf16r(c0.y), bf16r(c0.z), bf16r(c0.w),
                       bf16r(c1.x), bf16r(c1.y), bf16r(c1.z), bf16r(c1.w) };
        short8 af1 = { bf16r(c2.x), bf16r(c2.y), bf16r(c2.z), bf16r(c2.w),
                       bf16r(c3.x), bf16r(c3.y), bf16r(c3.z), bf16r(c3.w) };
        float4v acc0 = {0.f, 0.f, 0.f, 0.f}, acc1 = acc0, acc2 = acc0, acc3 = acc0;
        acc0 = __builtin_amdgcn_mfma_f32_16x16x32_bf16(af0, s0b0, acc0, 0, 0, 0);
        acc0 = __builtin_amdgcn_mfma_f32_16x16x32_bf16(af1, s1b0, acc0, 0, 0, 0);
        acc1 = __builtin_amdgcn_mfma_f32_16x16x32_bf16(af0, s0b1, acc1, 0, 0, 0);
        acc1 = __builtin_amdgcn_mfma_f32_16x16x32_bf16(af1, s1b1, acc1, 0, 0, 0);
        acc2 = __builtin_amdgcn_mfma_f32_16x16x32_bf16(af0, s0b2, acc2, 0, 0, 0);
        acc2 = __builtin_amdgcn_mfma_f32_16x16x32_bf16(af1, s1b2, acc2, 0, 0, 0);
        acc3 = __builtin_amdgcn_mfma_f32_16x16x32_bf16(af0, s0b3, acc3, 0, 0, 0);
        acc3 = __builtin_amdgcn_mfma_f32_16x16x32_bf16(af1, s1b3, acc3, 0, 0, 0);

        #define STASH(nb, A)                                                  \
            {                                                                 \
                _Pragma("unroll")                                             \
                for (int r = 0; r < 4; r++)                                   \
                    lred[wv * 1056 + (q * 4 + r) * 66 + nb * 16 + n15] = A[r]; \
            }
        STASH(0, acc0) STASH(1, acc1) STASH(2, acc2) STASH(3, acc3)
        #undef STASH
        p1 += __shfl_xor(p1, 16, 64); p1 += __shfl_xor(p1, 32, 64);
        p2 += __shfl_xor(p2, 16, 64); p2 += __shfl_xor(p2, 32, 64);
        if (q == 0) { lp[wv * 16 + n15] = p1; lp[64 + wv * 16 + n15] = p2; }
        __syncthreads();

        long i0 = (long)bx * 32 + rt * 16;
        int d = t & 63, ig = t >> 6;
        int bb = (int)(i0 >> 11);
        int il = (int)(i0 & (N - 1));
        float s0 = 0.f, s1 = 0.f, s2 = 0.f, s3 = 0.f;
        #pragma unroll
        for (int w = 0; w < 4; w++) {
            const float* lr = lred + w * 1056 + (ig * 4) * 66 + d;
            s0 += lr[0]; s1 += lr[66]; s2 += lr[132]; s3 += lr[198];
        }
        short4 pk = make_short4(bf16r(s0), bf16r(s1), bf16r(s2), bf16r(s3));
        int jj = il + ig * 4;
        *(short4*)(WhT + ((long)bb * DF + d) * N + jj) = pk;

        if (t < 16) {
            f1[i0 + t] = lp[t] + lp[16 + t] + lp[32 + t] + lp[48 + t];
        } else if (t < 32) {
            int tt = t + 48;   // 64 + (t-16)
            f2[i0 + t - 16] = lp[tt] + lp[16 + tt] + lp[32 + tt] + lp[48 + tt];
        }
        __syncthreads();
        c0 = m0; c1 = m1; c2 = m2; c3 = m3;
    }
}

// ---- D: partial denom slabs via max-identity — NO exp in inner loop. ----
__global__ __launch_bounds__(256) void k_denom(const float* __restrict__ f1,
                                               const float* __restrict__ f2,
                                               float* __restrict__ dpart) {
    __shared__ float2 le[ICH];
    int t = threadIdx.x;
    int b = blockIdx.z, ic = blockIdx.y;
    int j = blockIdx.x * 256 + t;
    float v = f1[b * N + ic * ICH + t];
    le[t] = make_float2(fexp2(v * LOG2E), fexp2(v * 0.2f * LOG2E));
    __syncthreads();
    float f2j = f2[b * N + j];
    float E2  = fexp2(f2j * LOG2E);
    float E2s = fexp2(f2j * 0.2f * LOG2E);
    float s = 0.f;
    const float4* le4 = (const float4*)le;
    for (int ii = 0; ii < ICH / 2; ii++) {
        float4 u = le4[ii];                 // {E1_i, E1s_i, E1_i+1, E1s_i+1}
        s += fmaxf(u.x * E2, u.y * E2s);
        s += fmaxf(u.z * E2, u.w * E2s);
    }
    dpart[((long)ic * B + b) * N + j] = s;
}

// ---- E: O = P @ Wh. R13: NO WhT LDS staging — B-frags stream directly
// from L2 with a 1-step register prefetch (4 independent dwordx4 per step;
// PE+MFMA ~140 cyc hides most of the ~200 cyc L2 latency, 2 waves/SIMD
// covers the rest). Only lc (per-group 512-j col consts, 16 KB total)
// lives in LDS, staged ONCE -> LDS-pipe insts halved, barriers 19 -> 4.
// Same global traffic as the staged version (64 MB L2 aggregate). ----
__global__ __launch_bounds__(512) void k_attn(const short* __restrict__ WhT,
                                              const float* __restrict__ f1,
                                              const float* __restrict__ f2,
                                              const float* __restrict__ dpart,
                                              float* __restrict__ out) {
    __shared__ __align__(16) unsigned char smem[34816];
    // lc: 4 groups x 512 float2 = 16 KB | epilogue: 4 x 32 x 68 floats = 34816 B
    int t = threadIdx.x;
    int wv = t >> 6, lane = t & 63;
    int g = wv >> 1, wg = wv & 1, lt2 = t & 127;
    int n15 = lane & 15, q = lane >> 4;
    int it = blockIdx.x, b = blockIdx.y;
    int i0 = it * 64 + wg * 32;

    // per-lane row factors for the wave's two 16-row sets
    float f1a = f1[b * N + i0 + n15];
    float f1b = f1[b * N + i0 + 16 + n15];
    float E1a = fexp2(f1a * LOG2E),  E1sa = fexp2(f1a * 0.2f * LOG2E);
    float E1b = fexp2(f1b * LOG2E),  E1sb = fexp2(f1b * 0.2f * LOG2E);

    float2* lc = (float2*)smem + g * 512;
    const float* f2b = f2 + b * N + g * 512;
    const float* dpb = dpart + b * N + g * 512;   // + ic*16384 per slice

    // ---- stage lc ONCE: 128 threads/group x 4 j each ----
    #pragma unroll
    for (int s = 0; s < 4; s++) {
        int j = s * 128 + lt2;
        float pf2 = f2b[j];
        float den = ((dpb[j] + dpb[16384 + j]) + (dpb[2 * 16384 + j] + dpb[3 * 16384 + j]))
                  + ((dpb[4 * 16384 + j] + dpb[5 * 16384 + j]) + (dpb[6 * 16384 + j] + dpb[7 * 16384 + j]));
        float rr = 1.0f / den;
        lc[j] = make_float2(fexp2(pf2 * LOG2E) * rr, fexp2(pf2 * 0.2f * LOG2E) * rr);
    }
    __syncthreads();

    // ---- main loop: 16 js-steps x 32 j, B-frags from L2 w/ reg prefetch ----
    const short* wb = WhT + (long)b * DF * N + (long)n15 * N + g * 512;
    short8 nb0 = *(const short8*)(wb + q * 8);
    short8 nb1 = *(const short8*)(wb + 16 * N + q * 8);
    short8 nb2 = *(const short8*)(wb + 32 * N + q * 8);
    short8 nb3 = *(const short8*)(wb + 48 * N + q * 8);

    float4v accA0 = {0.f, 0.f, 0.f, 0.f}, accA1 = accA0, accA2 = accA0, accA3 = accA0;
    float4v accB0 = accA0, accB1 = accA0, accB2 = accA0, accB3 = accA0;

    #pragma unroll 4
    for (int js = 0; js < 16; js++) {
        short8 b0 = nb0, b1 = nb1, b2 = nb2, b3 = nb3;
        if (js < 15) {                         // prefetch next step
            const short* bp = wb + (js + 1) * 32 + q * 8;
            nb0 = *(const short8*)(bp);
            nb1 = *(const short8*)(bp + 16 * N);
            nb2 = *(const short8*)(bp + 32 * N);
            nb3 = *(const short8*)(bp + 48 * N);
        }

        const float4* cp4 = (const float4*)(lc + js * 32 + q * 8);
        float4 p01 = cp4[0], p23 = cp4[1], p45 = cp4[2], p67 = cp4[3];
        short8 afA, afB;
        #define PE(px, py, DI) {                                  \
            afA[DI] = bf16r(fmaxf(E1a * (px), E1sa * (py)));      \
            afB[DI] = bf16r(fmaxf(E1b * (px), E1sb * (py)));      \
        }
        PE(p01.x, p01.y, 0) PE(p01.z, p01.w, 1)
        PE(p23.x, p23.y, 2) PE(p23.z, p23.w, 3)
        PE(p45.x, p45.y, 4) PE(p45.z, p45.w, 5)
        PE(p67.x, p67.y, 6) PE(p67.z, p67.w, 7)
        #undef PE

        accA0 = __builtin_amdgcn_mfma_f32_16x16x32_bf16(afA, b0, accA0, 0, 0, 0);
        accA1 = __builtin_amdgcn_mfma_f32_16x16x32_bf16(afA, b1, accA1, 0, 0, 0);
        accA2 = __builtin_amdgcn_mfma_f32_16x16x32_bf16(afA, b2, accA2, 0, 0, 0);
        accA3 = __builtin_amdgcn_mfma_f32_16x16x32_bf16(afA, b3, accA3, 0, 0, 0);
        accB0 = __builtin_amdgcn_mfma_f32_16x16x32_bf16(afB, b0, accB0, 0, 0, 0);
        accB1 = __builtin_amdgcn_mfma_f32_16x16x32_bf16(afB, b1, accB1, 0, 0, 0);
        accB2 = __builtin_amdgcn_mfma_f32_16x16x32_bf16(afB, b2, accB2, 0, 0, 0);
        accB3 = __builtin_amdgcn_mfma_f32_16x16x32_bf16(afB, b3, accB3, 0, 0, 0);
    }

    // ---- two-pass epilogue: reduce the 4 j-group partials via LDS ----
    float* epi = (float*)smem;   // 4 regions x (32 rows x 68) = 34816 B
    int row_o = t >> 3, d0 = (t & 7) * 8;
    int wg_o = row_o >> 5, r31 = row_o & 31;
    const float* e1p = epi + wg_o * 2176 + r31 * 68 + d0;
    const float* e2p = epi + (2 + wg_o) * 2176 + r31 * 68 + d0;

    #define ESTASH(rg) {                                                     \
        float* ep = epi + (rg) * 2176 + (q * 4) * 68 + n15;                  \
        _Pragma("unroll")                                                    \
        for (int r = 0; r < 4; r++) {                                        \
            ep[r * 68 +  0] = accA0[r]; ep[r * 68 + 16] = accA1[r];          \
            ep[r * 68 + 32] = accA2[r]; ep[r * 68 + 48] = accA3[r];          \
            ep[(16 * 68) + r * 68 +  0] = accB0[r];                          \
            ep[(16 * 68) + r * 68 + 16] = accB1[r];                          \
            ep[(16 * 68) + r * 68 + 32] = accB2[r];                          \
            ep[(16 * 68) + r * 68 + 48] = accB3[r];                          \
        }                                                                    \
    }

    __syncthreads();                 // all groups done reading lc
    if (g < 2) ESTASH(wv)            // regions 0..3 = waves 0..3
    __syncthreads();
    float4 sa0 = *(const float4*)(e1p);
    float4 sa1 = *(const float4*)(e1p + 4);
    float4 sb0 = *(const float4*)(e2p);
    float4 sb1 = *(const float4*)(e2p + 4);
    float4 t0, t1;
    t0.x = sa0.x + sb0.x; t0.y = sa0.y + sb0.y; t0.z = sa0.z + sb0.z; t0.w = sa0.w + sb0.w;
    t1.x = sa1.x + sb1.x; t1.y = sa1.y + sb1.y; t1.z = sa1.z + sb1.z; t1.w = sa1.w + sb1.w;
    __syncthreads();
    if (g >= 2) ESTASH(wv - 4)       // regions 0..3 = waves 4..7
    __syncthreads();
    #undef ESTASH
    float4 ua0 = *(const float4*)(e1p);
    float4 ua1 = *(const float4*)(e1p + 4);
    float4 ub0 = *(const float4*)(e2p);
    float4 ub1 = *(const float4*)(e2p + 4);
    float4 o0, o1;
    o0.x = eluf(t0.x + ua0.x + ub0.x); o0.y = eluf(t0.y + ua0.y + ub0.y);
    o0.z = eluf(t0.z + ua0.z + ub0.z); o0.w = eluf(t0.w + ua0.w + ub0.w);
    o1.x = eluf(t1.x + ua1.x + ub1.x); o1.y = eluf(t1.y + ua1.y + ub1.y);
    o1.z = eluf(t1.z + ua1.z + ub1.z); o1.w = eluf(t1.w + ua1.w + ub1.w);
    float* op = out + ((long)b * N + it * 64 + row_o) * DF + d0;
    *(float4*)(op) = o0;
    *(float4*)(op + 4) = o1;
}

extern "C" void kernel_launch(void* const* d_in, const int* in_sizes, int n_in,
                              void* d_out, int out_size, void* d_ws, size_t ws_size,
                              hipStream_t stream) {
    const float* h = (const float*)d_in[0];
    const float* W = (const float*)d_in[1];
    const float* a = (const float*)d_in[2];
    float* out = (float*)d_out;

    char* ws = (char*)d_ws;
    const size_t NB = (size_t)B * N;          // 16384 rows
    size_t off = 0;
    short* WhT   = (short*)(ws + off); off += NB * DF * sizeof(short);         // 2 MB
    float* f1    = (float*)(ws + off); off += NB * sizeof(float);
    float* f2    = (float*)(ws + off); off += NB * sizeof(float);
    float* dpart = (float*)(ws + off); off += (size_t)IC * NB * sizeof(float); // 512 KB
    (void)off; (void)ws_size;

    k_wh<<<NB / 32, 256, 0, stream>>>(h, W, a, WhT, f1, f2);
    k_denom<<<dim3(N / 256, IC, B), 256, 0, stream>>>(f1, f2, dpart);
    k_attn<<<dim3(N / 64, B), 512, 0, stream>>>(WhT, f1, f2, dpart, out);
}

// Round 14
// 91.511 us; speedup vs baseline: 1.0766x; 1.0766x over previous
//
#include <hip/hip_runtime.h>

#define B 8
#define N 2048
#define KF 256
#define DF 64
#define LOG2E 1.44269504088896340736f
#define IC 8
#define ICH (N / IC)   // 256

typedef __attribute__((ext_vector_type(8))) short short8;   // 8 bf16 (4 VGPRs)
typedef __attribute__((ext_vector_type(4))) float float4v;  // MFMA C/D frag

__device__ __forceinline__ float fexp2(float x) {
#if __has_builtin(__builtin_amdgcn_exp2f)
    return __builtin_amdgcn_exp2f(x);
#else
    return exp2f(x);
#endif
}
__device__ __forceinline__ float eluf(float x) {
    return x > 0.f ? x : fexp2(x * LOG2E) - 1.0f;
}
// float -> bf16 bits, round-half-up
__device__ __forceinline__ short bf16r(float x) {
    unsigned u = __float_as_uint(x);
    return (short)((u + 0x8000u) >> 16);
}
// pack 2 floats -> 2 bf16 in one unsigned (1 VALU op on gfx950)
__device__ __forceinline__ unsigned pkbf16(float x, float y) {
#if __has_builtin(__builtin_amdgcn_cvt_pk_bf16_f32)
    auto r = __builtin_amdgcn_cvt_pk_bf16_f32(x, y);
    return *(unsigned*)&r;
#else
    unsigned ux = (__float_as_uint(x) + 0x8000u) >> 16;
    unsigned uy = (__float_as_uint(y) + 0x8000u) & 0xffff0000u;
    return ux | uy;
#endif
}
#define DOT4(c, u, p) \
    p = fmaf(c.x, u.x, fmaf(c.y, u.y, fmaf(c.z, u.z, fmaf(c.w, u.w, p))));

// ---- A: Wh = h@W via MFMA + fused f1/f2 + fused W-prep (R11 structure).
// 512 blocks x 32 rows, K-split 4 across waves. Emits WhT chunk-major at
// 64-j granularity: WhT[b][j>>6][d][j&63] (8 KB contiguous chunks). ----
__global__ __launch_bounds__(256) void k_wh(const float* __restrict__ h,
                                            const float* __restrict__ W,
                                            const float* __restrict__ a,
                                            short* __restrict__ WhT,
                                            float* __restrict__ f1,
                                            float* __restrict__ f2) {
    __shared__ __align__(16) unsigned char smem[34816];  // phase union
    short* lwt  = (short*)smem;               // A: [64 n][256 k] bf16 W^T (32 KB)
    float* lv   = (float*)(smem + 32768);     // A: [2][256] v1,v2 (2 KB)
    float* lred = (float*)smem;               // B: [4 wv][16*66] (16.9 KB)
    float* lp   = (float*)(smem + 16896);     // B: [2][4][16]

    int t = threadIdx.x;
    int wv = t >> 6, lane = t & 63;
    int n15 = lane & 15, q = lane >> 4;
    int bx = blockIdx.x;

    // issue tile-0 h loads early (independent of W staging)
    const float* hr = h + ((long)bx * 32 + n15) * KF + wv * 64 + q * 8;
    float4 c0 = *(const float4*)(hr);
    float4 c1 = *(const float4*)(hr + 4);
    float4 c2 = *(const float4*)(hr + 32);
    float4 c3 = *(const float4*)(hr + 36);

    // ---- in-block W prep: thread t owns W row k=t ----
    {
        const float4* wr4 = (const float4*)(W + t * DF);
        float s1 = 0.f, s2 = 0.f;
        #pragma unroll
        for (int c = 0; c < 16; c++) {
            float4 w4 = wr4[c];
            float4 a1v = *(const float4*)(a + 4 * c);        // uniform -> s_load
            float4 a2v = *(const float4*)(a + DF + 4 * c);
            lwt[(4 * c + 0) * 256 + t] = bf16r(w4.x);        // 2-way write: free
            lwt[(4 * c + 1) * 256 + t] = bf16r(w4.y);
            lwt[(4 * c + 2) * 256 + t] = bf16r(w4.z);
            lwt[(4 * c + 3) * 256 + t] = bf16r(w4.w);
            s1 = fmaf(w4.x, a1v.x, fmaf(w4.y, a1v.y, fmaf(w4.z, a1v.z, fmaf(w4.w, a1v.w, s1))));
            s2 = fmaf(w4.x, a2v.x, fmaf(w4.y, a2v.y, fmaf(w4.z, a2v.z, fmaf(w4.w, a2v.w, s2))));
        }
        lv[t] = s1;
        lv[256 + t] = s2;
    }
    __syncthreads();

    // hoist loop-invariant B-frags + v12 (one-time LDS reads)
    const short* bq = lwt + n15 * 256 + wv * 64 + q * 8;
    short8 s0b0 = *(const short8*)(bq);
    short8 s0b1 = *(const short8*)(bq + 16 * 256);
    short8 s0b2 = *(const short8*)(bq + 32 * 256);
    short8 s0b3 = *(const short8*)(bq + 48 * 256);
    short8 s1b0 = *(const short8*)(bq + 32);
    short8 s1b1 = *(const short8*)(bq + 16 * 256 + 32);
    short8 s1b2 = *(const short8*)(bq + 32 * 256 + 32);
    short8 s1b3 = *(const short8*)(bq + 48 * 256 + 32);
    const float* vv = lv + wv * 64 + q * 8;
    float4 u00 = *(const float4*)(vv);
    float4 u01 = *(const float4*)(vv + 4);
    float4 u10 = *(const float4*)(vv + 32);
    float4 u11 = *(const float4*)(vv + 36);
    float4 x00 = *(const float4*)(vv + 256);
    float4 x01 = *(const float4*)(vv + 256 + 4);
    float4 x10 = *(const float4*)(vv + 256 + 32);
    float4 x11 = *(const float4*)(vv + 256 + 36);
    __syncthreads();   // lwt/lv dead; lred region reusable

    #pragma unroll
    for (int rt = 0; rt < 2; rt++) {
        float4 m0, m1, m2, m3;
        if (rt < 1) {                         // prefetch next 16-row tile
            const float* hn = hr + 16 * KF;
            m0 = *(const float4*)(hn);
            m1 = *(const float4*)(hn + 4);
            m2 = *(const float4*)(hn + 32);
            m3 = *(const float4*)(hn + 36);
        }
        float p1 = 0.f, p2 = 0.f;
        DOT4(c0, u00, p1) DOT4(c1, u01, p1) DOT4(c2, u10, p1) DOT4(c3, u11, p1)
        DOT4(c0, x00, p2) DOT4(c1, x01, p2) DOT4(c2, x10, p2) DOT4(c3, x11, p2)

        short8 af0 = { bf16r(c0.x), bf16r(c0.y), bf16r(c0.z), bf16r(c0.w),
                       bf16r(c1.x), bf16r(c1.y), bf16r(c1.z), bf16r(c1.w) };
        short8 af1 = { bf16r(c2.x), bf16r(c2.y), bf16r(c2.z), bf16r(c2.w),
                       bf16r(c3.x), bf16r(c3.y), bf16r(c3.z), bf16r(c3.w) };
        float4v acc0 = {0.f, 0.f, 0.f, 0.f}, acc1 = acc0, acc2 = acc0, acc3 = acc0;
        acc0 = __builtin_amdgcn_mfma_f32_16x16x32_bf16(af0, s0b0, acc0, 0, 0, 0);
        acc0 = __builtin_amdgcn_mfma_f32_16x16x32_bf16(af1, s1b0, acc0, 0, 0, 0);
        acc1 = __builtin_amdgcn_mfma_f32_16x16x32_bf16(af0, s0b1, acc1, 0, 0, 0);
        acc1 = __builtin_amdgcn_mfma_f32_16x16x32_bf16(af1, s1b1, acc1, 0, 0, 0);
        acc2 = __builtin_amdgcn_mfma_f32_16x16x32_bf16(af0, s0b2, acc2, 0, 0, 0);
        acc2 = __builtin_amdgcn_mfma_f32_16x16x32_bf16(af1, s1b2, acc2, 0, 0, 0);
        acc3 = __builtin_amdgcn_mfma_f32_16x16x32_bf16(af0, s0b3, acc3, 0, 0, 0);
        acc3 = __builtin_amdgcn_mfma_f32_16x16x32_bf16(af1, s1b3, acc3, 0, 0, 0);

        #define STASH(nb, A)                                                  \
            {                                                                 \
                _Pragma("unroll")                                             \
                for (int r = 0; r < 4; r++)                                   \
                    lred[wv * 1056 + (q * 4 + r) * 66 + nb * 16 + n15] = A[r]; \
            }
        STASH(0, acc0) STASH(1, acc1) STASH(2, acc2) STASH(3, acc3)
        #undef STASH
        p1 += __shfl_xor(p1, 16, 64); p1 += __shfl_xor(p1, 32, 64);
        p2 += __shfl_xor(p2, 16, 64); p2 += __shfl_xor(p2, 32, 64);
        if (q == 0) { lp[wv * 16 + n15] = p1; lp[64 + wv * 16 + n15] = p2; }
        __syncthreads();

        long i0 = (long)bx * 32 + rt * 16;
        int d = t & 63, ig = t >> 6;
        int bb = (int)(i0 >> 11);
        int il = (int)(i0 & (N - 1));
        float s0 = 0.f, s1 = 0.f, s2 = 0.f, s3 = 0.f;
        #pragma unroll
        for (int w = 0; w < 4; w++) {
            const float* lr = lred + w * 1056 + (ig * 4) * 66 + d;
            s0 += lr[0]; s1 += lr[66]; s2 += lr[132]; s3 += lr[198];
        }
        short4 pk = make_short4(bf16r(s0), bf16r(s1), bf16r(s2), bf16r(s3));
        int jj = il + ig * 4;
        *(short4*)(WhT + (((long)bb * 32 + (jj >> 6)) * 64 + d) * 64 + (jj & 63)) = pk;

        if (t < 16) {
            f1[i0 + t] = lp[t] + lp[16 + t] + lp[32 + t] + lp[48 + t];
        } else if (t < 32) {
            int tt = t + 48;   // 64 + (t-16)
            f2[i0 + t - 16] = lp[tt] + lp[16 + tt] + lp[32 + tt] + lp[48 + tt];
        }
        __syncthreads();
        c0 = m0; c1 = m1; c2 = m2; c3 = m3;
    }
}

// ---- D: partial denom slabs via max-identity — NO exp in inner loop:
// term = max(E1_i*E2_j, E1s_i*E2s_j), E1=2^(f1*L), E1s=2^(0.2*f1*L). ----
__global__ __launch_bounds__(256) void k_denom(const float* __restrict__ f1,
                                               const float* __restrict__ f2,
                                               float* __restrict__ dpart) {
    __shared__ float2 le[ICH];
    int t = threadIdx.x;
    int b = blockIdx.z, ic = blockIdx.y;
    int j = blockIdx.x * 256 + t;
    float v = f1[b * N + ic * ICH + t];
    le[t] = make_float2(fexp2(v * LOG2E), fexp2(v * 0.2f * LOG2E));
    __syncthreads();
    float f2j = f2[b * N + j];
    float E2  = fexp2(f2j * LOG2E);
    float E2s = fexp2(f2j * 0.2f * LOG2E);
    float s = 0.f;
    const float4* le4 = (const float4*)le;
    for (int ii = 0; ii < ICH / 2; ii++) {
        float4 u = le4[ii];                 // {E1_i, E1s_i, E1_i+1, E1s_i+1}
        s += fmaxf(u.x * E2, u.y * E2s);
        s += fmaxf(u.z * E2, u.w * E2s);
    }
    dpart[((long)ic * B + b) * N + j] = s;
}

// ---- E: O = P @ Wh (R12 structure — the 91.7 us best; R13's L2-direct
// streaming regressed +7 us: 16 cache lines per B-frag load, insufficient
// MLP. LDS staging with coalesced bulk loads wins — do not remove again).
// 256 blocks x 512 thr; 4 j-groups of 2 waves; each wave owns 32 i-rows
// (two A-frags share B-frags + lc reads). P entries via the max-identity;
// bf16 packing via v_cvt_pk_bf16_f32 (1 op / 2 values). 64-j chunks with
// register-prefetch pipeline; two-pass LDS epilogue (stride 68). ----
__global__ __launch_bounds__(512) void k_attn(const short* __restrict__ WhT,
                                              const float* __restrict__ f1,
                                              const float* __restrict__ f2,
                                              const float* __restrict__ dpart,
                                              float* __restrict__ out) {
    __shared__ __align__(16) unsigned char smem[40960];
    // ls: 4 groups x (64 rows x 9 uint4) = 36864 B; lc: 4 x 2 x 64 float2 = 4096 B
    int t = threadIdx.x;
    int wv = t >> 6, lane = t & 63;
    int g = wv >> 1, wg = wv & 1, lt2 = t & 127;
    int n15 = lane & 15, q = lane >> 4;
    int it = blockIdx.x, b = blockIdx.y;
    int i0 = it * 64 + wg * 32;

    // per-lane row factors for the wave's two 16-row sets
    float f1a = f1[b * N + i0 + n15];
    float f1b = f1[b * N + i0 + 16 + n15];
    float E1a = fexp2(f1a * LOG2E),  E1sa = fexp2(f1a * 0.2f * LOG2E);
    float E1b = fexp2(f1b * LOG2E),  E1sb = fexp2(f1b * 0.2f * LOG2E);

    uint4*  ls = (uint4*)smem + g * 576;                    // 64 rows x 9
    float2* lc = (float2*)(smem + 36864) + g * 128;         // [2][64]
    const uint4* wsrc = (const uint4*)WhT + ((long)b * 32 + g * 8) * 512;
    const float* f2b = f2 + b * N + g * 512;
    const float* dpb = dpart + b * N + g * 512;   // + ic*16384 per slice

    uint4 r0, r1, r2, r3;
    float pf2, pd0, pd1, pd2, pd3, pd4, pd5, pd6, pd7;

    #define LOADC(cc) {                                     \
        const uint4* gp = wsrc + (cc) * 512;                \
        r0 = gp[lt2];       r1 = gp[128 + lt2];             \
        r2 = gp[256 + lt2]; r3 = gp[384 + lt2];             \
    }
    #define LOADP(cc) {                                     \
        if (lt2 < 64) {                                     \
            int jb2 = (cc) * 64 + lt2;                      \
            pf2 = f2b[jb2];                                 \
            pd0 = dpb[jb2];              pd1 = dpb[16384 + jb2]; \
            pd2 = dpb[2 * 16384 + jb2];  pd3 = dpb[3 * 16384 + jb2]; \
            pd4 = dpb[4 * 16384 + jb2];  pd5 = dpb[5 * 16384 + jb2]; \
            pd6 = dpb[6 * 16384 + jb2];  pd7 = dpb[7 * 16384 + jb2]; \
        }                                                   \
    }
    #define STOREC() {                                      \
        int rb = lt2 >> 3, cl = lt2 & 7;                    \
        ls[rb * 9 + cl] = r0;        ls[(16 + rb) * 9 + cl] = r1; \
        ls[(32 + rb) * 9 + cl] = r2; ls[(48 + rb) * 9 + cl] = r3; \
    }
    #define LCC(buf) {                                      \
        if (lt2 < 64) {                                     \
            float den = ((pd0 + pd1) + (pd2 + pd3)) + ((pd4 + pd5) + (pd6 + pd7)); \
            float rr = 1.0f / den;                          \
            float E2  = fexp2(pf2 * LOG2E);                 \
            float E2s = fexp2(pf2 * 0.2f * LOG2E);          \
            lc[(buf) * 64 + lt2] = make_float2(E2 * rr, E2s * rr); \
        }                                                   \
    }

    LOADC(0) LOADP(0)
    STOREC() LCC(0)
    __syncthreads();

    float4v accA0 = {0.f, 0.f, 0.f, 0.f}, accA1 = accA0, accA2 = accA0, accA3 = accA0;
    float4v accB0 = accA0, accB1 = accA0, accB2 = accA0, accB3 = accA0;

    for (int c = 0; c < 8; c++) {
        int cur = c & 1;
        if (c < 7) { LOADC(c + 1) LOADP(c + 1) }   // in flight during compute

        const short* lsS = (const short*)ls;
        const float4* lcf = (const float4*)(lc + cur * 64);
        #pragma unroll
        for (int js = 0; js < 2; js++) {
            const float4* cp4 = lcf + js * 16 + q * 4;   // 8 j as 4 float4
            float4 p01 = cp4[0], p23 = cp4[1], p45 = cp4[2], p67 = cp4[3];
            float A0 = fmaxf(E1a * p01.x, E1sa * p01.y);
            float A1 = fmaxf(E1a * p01.z, E1sa * p01.w);
            float A2 = fmaxf(E1a * p23.x, E1sa * p23.y);
            float A3 = fmaxf(E1a * p23.z, E1sa * p23.w);
            float A4 = fmaxf(E1a * p45.x, E1sa * p45.y);
            float A5 = fmaxf(E1a * p45.z, E1sa * p45.w);
            float A6 = fmaxf(E1a * p67.x, E1sa * p67.y);
            float A7 = fmaxf(E1a * p67.z, E1sa * p67.w);
            float B0 = fmaxf(E1b * p01.x, E1sb * p01.y);
            float B1 = fmaxf(E1b * p01.z, E1sb * p01.w);
            float B2 = fmaxf(E1b * p23.x, E1sb * p23.y);
            float B3 = fmaxf(E1b * p23.z, E1sb * p23.w);
            float B4 = fmaxf(E1b * p45.x, E1sb * p45.y);
            float B5 = fmaxf(E1b * p45.z, E1sb * p45.w);
            float B6 = fmaxf(E1b * p67.x, E1sb * p67.y);
            float B7 = fmaxf(E1b * p67.z, E1sb * p67.w);
            uint4 ua = { pkbf16(A0, A1), pkbf16(A2, A3), pkbf16(A4, A5), pkbf16(A6, A7) };
            uint4 ub = { pkbf16(B0, B1), pkbf16(B2, B3), pkbf16(B4, B5), pkbf16(B6, B7) };
            short8 afA = *(short8*)&ua;
            short8 afB = *(short8*)&ub;

            const short* bp = lsS + js * 32 + q * 8;   // + d*72 shorts per row
            short8 b0 = *(const short8*)(bp + (n15 +  0) * 72);
            short8 b1 = *(const short8*)(bp + (n15 + 16) * 72);
            short8 b2 = *(const short8*)(bp + (n15 + 32) * 72);
            short8 b3 = *(const short8*)(bp + (n15 + 48) * 72);

            accA0 = __builtin_amdgcn_mfma_f32_16x16x32_bf16(afA, b0, accA0, 0, 0, 0);
            accA1 = __builtin_amdgcn_mfma_f32_16x16x32_bf16(afA, b1, accA1, 0, 0, 0);
            accA2 = __builtin_amdgcn_mfma_f32_16x16x32_bf16(afA, b2, accA2, 0, 0, 0);
            accA3 = __builtin_amdgcn_mfma_f32_16x16x32_bf16(afA, b3, accA3, 0, 0, 0);
            accB0 = __builtin_amdgcn_mfma_f32_16x16x32_bf16(afB, b0, accB0, 0, 0, 0);
            accB1 = __builtin_amdgcn_mfma_f32_16x16x32_bf16(afB, b1, accB1, 0, 0, 0);
            accB2 = __builtin_amdgcn_mfma_f32_16x16x32_bf16(afB, b2, accB2, 0, 0, 0);
            accB3 = __builtin_amdgcn_mfma_f32_16x16x32_bf16(afB, b3, accB3, 0, 0, 0);
        }

        if (c < 7) {
            __syncthreads();
            STOREC() LCC((c + 1) & 1)
            __syncthreads();
        }
    }
    #undef LOADC
    #undef LOADP
    #undef STOREC
    #undef LCC

    // ---- two-pass epilogue: reduce the 4 j-group partials via LDS ----
    float* epi = (float*)smem;   // 4 regions x (32 rows x 68) = 34816 B
    int row_o = t >> 3, d0 = (t & 7) * 8;
    int wg_o = row_o >> 5, r31 = row_o & 31;
    const float* e1p = epi + wg_o * 2176 + r31 * 68 + d0;
    const float* e2p = epi + (2 + wg_o) * 2176 + r31 * 68 + d0;

    #define ESTASH(rg) {                                                     \
        float* ep = epi + (rg) * 2176 + (q * 4) * 68 + n15;                  \
        _Pragma("unroll")                                                    \
        for (int r = 0; r < 4; r++) {                                        \
            ep[r * 68 +  0] = accA0[r]; ep[r * 68 + 16] = accA1[r];          \
            ep[r * 68 + 32] = accA2[r]; ep[r * 68 + 48] = accA3[r];          \
            ep[(16 * 68) + r * 68 +  0] = accB0[r];                          \
            ep[(16 * 68) + r * 68 + 16] = accB1[r];                          \
            ep[(16 * 68) + r * 68 + 32] = accB2[r];                          \
            ep[(16 * 68) + r * 68 + 48] = accB3[r];                          \
        }                                                                    \
    }

    __syncthreads();                 // all groups done reading ls
    if (g < 2) ESTASH(wv)            // regions 0..3 = waves 0..3
    __syncthreads();
    float4 sa0 = *(const float4*)(e1p);
    float4 sa1 = *(const float4*)(e1p + 4);
    float4 sb0 = *(const float4*)(e2p);
    float4 sb1 = *(const float4*)(e2p + 4);
    float4 t0, t1;
    t0.x = sa0.x + sb0.x; t0.y = sa0.y + sb0.y; t0.z = sa0.z + sb0.z; t0.w = sa0.w + sb0.w;
    t1.x = sa1.x + sb1.x; t1.y = sa1.y + sb1.y; t1.z = sa1.z + sb1.z; t1.w = sa1.w + sb1.w;
    __syncthreads();
    if (g >= 2) ESTASH(wv - 4)       // regions 0..3 = waves 4..7
    __syncthreads();
    #undef ESTASH
    float4 ua0 = *(const float4*)(e1p);
    float4 ua1 = *(const float4*)(e1p + 4);
    float4 ub0 = *(const float4*)(e2p);
    float4 ub1 = *(const float4*)(e2p + 4);
    float4 o0, o1;
    o0.x = eluf(t0.x + ua0.x + ub0.x); o0.y = eluf(t0.y + ua0.y + ub0.y);
    o0.z = eluf(t0.z + ua0.z + ub0.z); o0.w = eluf(t0.w + ua0.w + ub0.w);
    o1.x = eluf(t1.x + ua1.x + ub1.x); o1.y = eluf(t1.y + ua1.y + ub1.y);
    o1.z = eluf(t1.z + ua1.z + ub1.z); o1.w = eluf(t1.w + ua1.w + ub1.w);
    float* op = out + ((long)b * N + it * 64 + row_o) * DF + d0;
    *(float4*)(op) = o0;
    *(float4*)(op + 4) = o1;
}

extern "C" void kernel_launch(void* const* d_in, const int* in_sizes, int n_in,
                              void* d_out, int out_size, void* d_ws, size_t ws_size,
                              hipStream_t stream) {
    const float* h = (const float*)d_in[0];
    const float* W = (const float*)d_in[1];
    const float* a = (const float*)d_in[2];
    float* out = (float*)d_out;

    char* ws = (char*)d_ws;
    const size_t NB = (size_t)B * N;          // 16384 rows
    size_t off = 0;
    short* WhT   = (short*)(ws + off); off += NB * DF * sizeof(short);         // 2 MB
    float* f1    = (float*)(ws + off); off += NB * sizeof(float);
    float* f2    = (float*)(ws + off); off += NB * sizeof(float);
    float* dpart = (float*)(ws + off); off += (size_t)IC * NB * sizeof(float); // 512 KB
    (void)off; (void)ws_size;

    k_wh<<<NB / 32, 256, 0, stream>>>(h, W, a, WhT, f1, f2);
    k_denom<<<dim3(N / 256, IC, B), 256, 0, stream>>>(f1, f2, dpart);
    k_attn<<<dim3(N / 64, B), 512, 0, stream>>>(WhT, f1, f2, dpart, out);
}